// Round 15
// baseline (345.043 us; speedup 1.0000x reference)
//
#include <hip/hip_runtime.h>

#define S_ 2048
#define D_ 1024

typedef unsigned short u16;
typedef unsigned int u32;
typedef __bf16 bf16x8 __attribute__((ext_vector_type(8)));
typedef unsigned short us8 __attribute__((ext_vector_type(8)));
typedef unsigned short us4 __attribute__((ext_vector_type(4)));
typedef unsigned int u32x4 __attribute__((ext_vector_type(4)));
typedef float f32x4 __attribute__((ext_vector_type(4)));
typedef float f32x16 __attribute__((ext_vector_type(16)));

#if __has_builtin(__builtin_amdgcn_exp2f)
#define EXP2(x) __builtin_amdgcn_exp2f(x)
#else
#define EXP2(x) exp2f(x)
#endif

static __device__ __forceinline__ u16 f2bf(float f) {
  unsigned u = __builtin_bit_cast(unsigned, f);
  u += 0x7fffu + ((u >> 16) & 1u);   // RNE; inputs are finite
  return (u16)(u >> 16);
}

static __device__ __forceinline__ float bf2f(u16 h) {
  return __builtin_bit_cast(float, (u32)h << 16);
}

static __device__ __forceinline__ unsigned cvtpk_bf16(float lo, float hi) {
  unsigned r;
  asm("v_cvt_pk_bf16_f32 %0, %1, %2" : "=v"(r) : "v"(lo), "v"(hi));
  return r;
}

static __device__ __forceinline__ f32x4 mfma16(bf16x8 a, bf16x8 b, f32x4 c) {
  return __builtin_amdgcn_mfma_f32_16x16x32_bf16(a, b, c, 0, 0, 0);
}

static __device__ __forceinline__ f32x16 mfma32(bf16x8 a, bf16x8 b, f32x16 c) {
  return __builtin_amdgcn_mfma_f32_32x32x16_bf16(a, b, c, 0, 0, 0);
}

static __device__ __forceinline__ void gload16(const void* g, void* lds) {
  // async global->LDS, 16B/lane; LDS dest = wave-uniform base + lane*16
  __builtin_amdgcn_global_load_lds((const __attribute__((address_space(1))) void*)g,
                                   (__attribute__((address_space(3))) void*)lds, 16, 0, 0);
}

// -------- fused prep: ln1 (8192 rows) + 6 weight transposes (64k x 32n tiles, us8 writes)
// -------- + bias concat, ONE launch --------
__global__ __launch_bounds__(256) void prep_kernel(
    const float* __restrict__ x, u16* __restrict__ xA, const float* __restrict__ ln1a,
    const float* __restrict__ ln1b, const float* __restrict__ wq, const float* __restrict__ wk,
    const float* __restrict__ wv, const float* __restrict__ wo, const float* __restrict__ w1,
    const float* __restrict__ w2, const float* __restrict__ bq, const float* __restrict__ bk,
    const float* __restrict__ bv, u16* __restrict__ wqkv, u16* __restrict__ wot,
    u16* __restrict__ w1t, u16* __restrict__ w2t, float* __restrict__ bcat, float qs) {
  const int bid = blockIdx.x;
  const int tid = threadIdx.y * 32 + threadIdx.x;
  if (bid < 8192) {  // ---- ln1 row ----
    const int row = bid;
    const float4 v = *(const float4*)(x + (size_t)row * D_ + tid * 4);
    float s = v.x + v.y + v.z + v.w;
    float ss = v.x * v.x + v.y * v.y + v.z * v.z + v.w * v.w;
#pragma unroll
    for (int off = 32; off >= 1; off >>= 1) {
      s += __shfl_xor(s, off);
      ss += __shfl_xor(ss, off);
    }
    __shared__ float red[8];
    const int w = tid >> 6, lane = tid & 63;
    if (lane == 0) { red[w] = s; red[4 + w] = ss; }
    __syncthreads();
    s = red[0] + red[1] + red[2] + red[3];
    ss = red[4] + red[5] + red[6] + red[7];
    const float mean = s * (1.0f / D_);
    const float var = (ss - s * mean) * (1.0f / (D_ - 1));
    const float inv = 1.0f / (sqrtf(var) + 1e-6f);
    const int j = tid * 4;
    const float4 av = *(const float4*)(ln1a + j);
    const float4 bv = *(const float4*)(ln1b + j);
    us4 o;
    o[0] = f2bf((v.x - mean) * inv * av.x + bv.x);
    o[1] = f2bf((v.y - mean) * inv * av.y + bv.y);
    o[2] = f2bf((v.z - mean) * inv * av.z + bv.z);
    o[3] = f2bf((v.w - mean) * inv * av.w + bv.w);
    *(us4*)(xA + (size_t)row * D_ + j) = o;
    return;
  }
  if (bid >= 14336) {  // ---- bias concat: 12 blocks x 256 ----
    const int i = (bid - 14336) * 256 + tid;
    bcat[i] = (i < 1024) ? bq[i] * qs : ((i < 2048) ? bk[i - 1024] : bv[i - 2048]);
    return;
  }
  // ---- weight transpose: tile = 64 k x 32 n ----
  const int tb = bid - 8192;
  const float* in;
  u16* out;
  int K, N, idx;
  float sc = 1.0f;
  if (tb < 2048) {
    K = 1024; N = 1024; idx = tb & 511;
    if (tb < 512)        { in = wq; out = wqkv;             sc = qs; }
    else if (tb < 1024)  { in = wk; out = wqkv + (1 << 20); }
    else if (tb < 1536)  { in = wv; out = wqkv + (2 << 20); }
    else                 { in = wo; out = wot; }
  } else if (tb < 4096) {
    in = w1; out = w1t; K = 1024; N = 4096; idx = tb - 2048;
  } else {
    in = w2; out = w2t; K = 4096; N = 1024; idx = tb - 4096;
  }
  const int nk = K >> 6;
  const int k0 = (idx % nk) * 64, n0 = (idx / nk) * 32;
  __shared__ float t[32][65];
  const int kk = tid >> 2, nj = (tid & 3) * 8;
  const float* src = in + (size_t)(k0 + kk) * N + n0 + nj;
  const float4 v0 = *(const float4*)(src);
  const float4 v1 = *(const float4*)(src + 4);
  t[nj + 0][kk] = v0.x; t[nj + 1][kk] = v0.y; t[nj + 2][kk] = v0.z; t[nj + 3][kk] = v0.w;
  t[nj + 4][kk] = v1.x; t[nj + 5][kk] = v1.y; t[nj + 6][kk] = v1.z; t[nj + 7][kk] = v1.w;
  __syncthreads();
  const int row = tid >> 3, kb = (tid & 7) * 8;
  us8 o;
#pragma unroll
  for (int j = 0; j < 8; j++) o[j] = f2bf(t[row][kb + j] * sc);
  *(us8*)(out + (size_t)(n0 + row) * K + k0 + kb) = o;
}

// ---------------- LayerNorm (bf16 input variant for ln2) ----------------
__global__ __launch_bounds__(256) void ln_bf16_kernel(const u16* __restrict__ in,
                                                      u16* __restrict__ out,
                                                      const float* __restrict__ alpha,
                                                      const float* __restrict__ beta) {
  const int row = blockIdx.x;
  const int tid = threadIdx.x;
  const us4 h = *(const us4*)(in + (size_t)row * D_ + tid * 4);
  float v0 = bf2f(h[0]), v1 = bf2f(h[1]), v2 = bf2f(h[2]), v3 = bf2f(h[3]);
  float s = v0 + v1 + v2 + v3;
  float ss = v0 * v0 + v1 * v1 + v2 * v2 + v3 * v3;
#pragma unroll
  for (int off = 32; off >= 1; off >>= 1) {
    s += __shfl_xor(s, off);
    ss += __shfl_xor(ss, off);
  }
  __shared__ float red[8];
  const int w = tid >> 6, lane = tid & 63;
  if (lane == 0) { red[w] = s; red[4 + w] = ss; }
  __syncthreads();
  s = red[0] + red[1] + red[2] + red[3];
  ss = red[4] + red[5] + red[6] + red[7];
  const float mean = s * (1.0f / D_);
  const float var = (ss - s * mean) * (1.0f / (D_ - 1));
  const float inv = 1.0f / (sqrtf(var) + 1e-6f);
  const int j = tid * 4;
  const float4 av = *(const float4*)(alpha + j);
  const float4 bv = *(const float4*)(beta + j);
  us4 o;
  o[0] = f2bf((v0 - mean) * inv * av.x + bv.x);
  o[1] = f2bf((v1 - mean) * inv * av.y + bv.y);
  o[2] = f2bf((v2 - mean) * inv * av.z + bv.z);
  o[3] = f2bf((v3 - mean) * inv * av.w + bv.w);
  *(us4*)(out + (size_t)row * D_ + j) = o;
}

// -------- GEMM 128x128, 32x32x16 MFMA: 2-buffer, counted vmcnt(8), 64KB LDS --------
// 4 waves (2M x 2N), wave = 64x64 = 2x2 frags of 32x32. 16 MFMA + 16 ds_read_b128 / tile.
// A/B frag: row|col = lane&31, k-half = lane>>5. C/D: col=lane&31,
// row=(reg&3)+8*(reg>>2)+4*(lane>>5) [HW-verified m74/m101].
// OM: 0 = bf16 out, 1 = f32 out. RESID: 0 none, 1 f32, 2 bf16.
template <int OM, int RESID>
__global__ __launch_bounds__(256, 2) void gemm_bt128(const u16* __restrict__ A,
                                                     const u16* __restrict__ Bt,
                                                     const float* __restrict__ bias,
                                                     const void* __restrict__ resid,
                                                     void* __restrict__ outp, int N, int K) {
  __shared__ u16 lds[2 * 16384];  // 2 x (A 128x64 + B 128x64) u16 = 64 KiB
  const int tid = threadIdx.x;
  const int lane = tid & 63, w = tid >> 6;
  const int l31 = lane & 31, hi = lane >> 5;
  const int wr = w >> 1, wc = w & 1;  // 2M x 2N
  const int gx = gridDim.x;
  const int nwg = gx * gridDim.y;
  const int orig = blockIdx.y * gx + blockIdx.x;
  const int nid = (orig & 7) * (nwg >> 3) + (orig >> 3);  // nwg % 8 == 0
  const int bx = nid % gx, by = nid / gx;
  const size_t row0 = (size_t)by * 128;
  const int col0 = bx * 128;

  float biasv[2];
#pragma unroll
  for (int n = 0; n < 2; n++) biasv[n] = bias[col0 + wc * 64 + n * 32 + l31];

  f32x16 acc[2][2];
#pragma unroll
  for (int m = 0; m < 2; m++)
#pragma unroll
    for (int n = 0; n < 2; n++)
#pragma unroll
      for (int q = 0; q < 16; q++) acc[m][n][q] = biasv[n];

  const int lrow = tid >> 3;                       // 0..31 (row within 32-row chunk)
  const int scol = 8 * ((tid & 7) ^ (lrow & 7));   // pre-swizzled source col
  const u16* gA = A + (row0 + lrow) * (size_t)K + scol;
  const u16* gB = Bt + ((size_t)col0 + lrow) * (size_t)K + scol;
  const int nt = K >> 6;

  {
    u16* d = lds + w * 512;
#pragma unroll
    for (int j = 0; j < 4; j++) gload16(gA + (size_t)(j * 32) * K, d + j * 2048);
#pragma unroll
    for (int j = 0; j < 4; j++) gload16(gB + (size_t)(j * 32) * K, d + 8192 + j * 2048);
  }

  for (int t = 0; t < nt; ++t) {
    const u16* As_ = lds + (t & 1) * 16384;
    const u16* Bs_ = As_ + 8192;
    if (t + 1 < nt) {
      u16* d = lds + ((t + 1) & 1) * 16384 + w * 512;
      const size_t ko = (size_t)(t + 1) * 64;
#pragma unroll
      for (int j = 0; j < 4; j++) gload16(gA + (size_t)(j * 32) * K + ko, d + j * 2048);
#pragma unroll
      for (int j = 0; j < 4; j++) gload16(gB + (size_t)(j * 32) * K + ko, d + 8192 + j * 2048);
      asm volatile("s_waitcnt vmcnt(8)" ::: "memory");
    } else {
      asm volatile("s_waitcnt vmcnt(0)" ::: "memory");
    }
    __builtin_amdgcn_s_barrier();
    asm volatile("" ::: "memory");

    // all B frags: bfr[ks][n], slot = (ks*2 + hi) ^ (row&7)
    bf16x8 bfr[4][2];
#pragma unroll
    for (int ks = 0; ks < 4; ks++)
#pragma unroll
      for (int n = 0; n < 2; n++) {
        const int row = wc * 64 + n * 32 + l31;
        bfr[ks][n] = __builtin_bit_cast(
            bf16x8, *(const us8*)(Bs_ + row * 64 + (((ks * 2 + hi) ^ (row & 7)) << 3)));
      }

#pragma unroll
    for (int p = 0; p < 4; ++p) {  // p = ks
      bf16x8 af[2];
#pragma unroll
      for (int m = 0; m < 2; m++) {
        const int row = wr * 64 + m * 32 + l31;
        af[m] = __builtin_bit_cast(
            bf16x8, *(const us8*)(As_ + row * 64 + (((p * 2 + hi) ^ (row & 7)) << 3)));
      }
      asm volatile("" ::: "memory");
      if (p > 0) __builtin_amdgcn_s_barrier();  // barrier-wait hides the ds_read latency
      asm volatile("s_waitcnt lgkmcnt(0)" ::: "memory");
      __builtin_amdgcn_sched_barrier(0);  // rule 18
      __builtin_amdgcn_s_setprio(1);
#pragma unroll
      for (int m = 0; m < 2; m++)
#pragma unroll
        for (int n = 0; n < 2; n++) acc[m][n] = mfma32(af[m], bfr[p][n], acc[m][n]);
      __builtin_amdgcn_s_setprio(0);
    }
    asm volatile("" ::: "memory");
    __builtin_amdgcn_s_barrier();  // tile boundary
  }

#pragma unroll
  for (int m = 0; m < 2; m++)
#pragma unroll
    for (int n = 0; n < 2; n++) {
      const int cg = col0 + wc * 64 + n * 32 + l31;
#pragma unroll
      for (int q = 0; q < 16; q++) {
        const size_t rg = row0 + wr * 64 + m * 32 + (q & 3) + 8 * (q >> 2) + 4 * hi;
        float v = acc[m][n][q];
        if (RESID == 1) v += ((const float*)resid)[rg * N + cg];
        if (RESID == 2) v += bf2f(((const u16*)resid)[rg * N + cg]);
        if (OM == 1)
          ((float*)outp)[rg * N + cg] = v;
        else
          ((u16*)outp)[rg * N + cg] = f2bf(v);
      }
    }
}

// -------- GEMM 256x256, 32x32x16 MFMA: 2-buffer, 4-phase, vmcnt(8) --------
// 8 waves (2M x 4N), wave = 128x64 = 4x2 frags of 32x32.
// OM: 0 = bf16 out (+RELU), 2 = fused QKV (seg0->q, seg1->k, seg2->V^T key-permuted)
template <int OM, bool RELU>
__global__ __launch_bounds__(512, 2) void gemm_bt256(const u16* __restrict__ A,
                                                     const u16* __restrict__ Bt,
                                                     const float* __restrict__ bias,
                                                     void* __restrict__ outp,
                                                     void* __restrict__ out1,
                                                     void* __restrict__ out2, int N, int K) {
  __shared__ u16 lds[2 * 32768];
  const int tid = threadIdx.x;
  const int lane = tid & 63, w = tid >> 6;
  const int l31 = lane & 31, hi = lane >> 5;
  const int wr = w >> 2, wc = w & 3;  // 2M x 4N
  const int gx = gridDim.x;
  const int nwg = gx * gridDim.y;
  const int orig = blockIdx.y * gx + blockIdx.x;
  const int nid = (orig & 7) * (nwg >> 3) + (orig >> 3);
  const int bx = nid % gx, by = nid / gx;
  const size_t row0 = (size_t)by * 256;
  const int col0 = bx * 256;

  float biasv[2];
#pragma unroll
  for (int n = 0; n < 2; n++) biasv[n] = bias[col0 + wc * 64 + n * 32 + l31];

  f32x16 acc[4][2];
#pragma unroll
  for (int m = 0; m < 4; m++)
#pragma unroll
    for (int n = 0; n < 2; n++)
#pragma unroll
      for (int q = 0; q < 16; q++) acc[m][n][q] = biasv[n];

  const int lrow = tid >> 3;                       // 0..63
  const int scol = 8 * ((tid & 7) ^ (lrow & 7));   // pre-swizzled source col
  const u16* gA = A + (row0 + lrow) * (size_t)K + scol;
  const u16* gB = Bt + ((size_t)col0 + lrow) * (size_t)K + scol;
  const int nt = K >> 6;

  {
    u16* d = lds + w * 512;
#pragma unroll
    for (int j = 0; j < 4; j++) gload16(gA + (size_t)(j * 64) * K, d + j * 4096);
#pragma unroll
    for (int j = 0; j < 4; j++) gload16(gB + (size_t)(j * 64) * K, d + 16384 + j * 4096);
  }

  for (int t = 0; t < nt; ++t) {
    const u16* As_ = lds + (t & 1) * 32768;
    const u16* Bs_ = As_ + 16384;
    if (t + 1 < nt) {
      u16* d = lds + ((t + 1) & 1) * 32768 + w * 512;
      const size_t ko = (size_t)(t + 1) * 64;
#pragma unroll
      for (int j = 0; j < 4; j++) gload16(gA + (size_t)(j * 64) * K + ko, d + j * 4096);
#pragma unroll
      for (int j = 0; j < 4; j++) gload16(gB + (size_t)(j * 64) * K + ko, d + 16384 + j * 4096);
      asm volatile("s_waitcnt vmcnt(8)" ::: "memory");
    } else {
      asm volatile("s_waitcnt vmcnt(0)" ::: "memory");
    }
    __builtin_amdgcn_s_barrier();
    asm volatile("" ::: "memory");

    bf16x8 bfr[4][2];
#pragma unroll
    for (int ks = 0; ks < 4; ks++)
#pragma unroll
      for (int n = 0; n < 2; n++) {
        const int row = wc * 64 + n * 32 + l31;
        bfr[ks][n] = __builtin_bit_cast(
            bf16x8, *(const us8*)(Bs_ + row * 64 + (((ks * 2 + hi) ^ (row & 7)) << 3)));
      }

#pragma unroll
    for (int p = 0; p < 4; ++p) {  // p = ks
      bf16x8 af[4];
#pragma unroll
      for (int m = 0; m < 4; m++) {
        const int row = wr * 128 + m * 32 + l31;
        af[m] = __builtin_bit_cast(
            bf16x8, *(const us8*)(As_ + row * 64 + (((p * 2 + hi) ^ (row & 7)) << 3)));
      }
      asm volatile("" ::: "memory");
      if (p > 0) __builtin_amdgcn_s_barrier();
      asm volatile("s_waitcnt lgkmcnt(0)" ::: "memory");
      __builtin_amdgcn_sched_barrier(0);
      __builtin_amdgcn_s_setprio(1);
#pragma unroll
      for (int m = 0; m < 4; m++)
#pragma unroll
        for (int n = 0; n < 2; n++) acc[m][n] = mfma32(af[m], bfr[p][n], acc[m][n]);
      __builtin_amdgcn_s_setprio(0);
    }
    asm volatile("" ::: "memory");
    __builtin_amdgcn_s_barrier();
  }

#pragma unroll
  for (int m = 0; m < 4; m++)
#pragma unroll
    for (int n = 0; n < 2; n++) {
      if (OM == 2) {
        const int seg = col0 >> 10;
        const int cl = (col0 & 1023) + wc * 64 + n * 32 + l31;
        if (seg == 2) {
          // V^T [b,head,hd,s'] key-permuted; reg-quads are 4 consecutive rows -> us4
          const int head = cl >> 6, hd = cl & 63;
#pragma unroll
          for (int qq = 0; qq < 4; qq++) {
            const size_t rg0 = row0 + wr * 128 + m * 32 + 8 * qq + 4 * hi;
            const int b = (int)(rg0 >> 11), s0 = (int)(rg0 & 2047);
            const int s0p = (s0 & ~63) | (s0 & 32) | ((s0 << 1) & 24) | ((s0 >> 2) & 4);
            us4 o;
#pragma unroll
            for (int i = 0; i < 4; i++) o[i] = f2bf(acc[m][n][qq * 4 + i]);
            *(us4*)((u16*)out2 + (((size_t)(b * 16 + head) * 64 + hd) * S_ + s0p)) = o;
          }
        } else {
          u16* dst = (u16*)(seg == 0 ? outp : out1);
#pragma unroll
          for (int q = 0; q < 16; q++) {
            const size_t rg = row0 + wr * 128 + m * 32 + (q & 3) + 8 * (q >> 2) + 4 * hi;
            dst[rg * D_ + cl] = f2bf(acc[m][n][q]);
          }
        }
      } else {
        const int cg = col0 + wc * 64 + n * 32 + l31;
#pragma unroll
        for (int q = 0; q < 16; q++) {
          const size_t rg = row0 + wr * 128 + m * 32 + (q & 3) + 8 * (q >> 2) + 4 * hi;
          float v = acc[m][n][q];
          if (RELU) v = fmaxf(v, 0.0f);
          ((u16*)outp)[rg * N + cg] = f2bf(v);
        }
      }
    }
}

// ------------- Flash attention: KVBLK=128, 8 waves/block (4 waves/SIMD occupancy) ---------
__global__ __launch_bounds__(512) void attn_kernel(const u16* __restrict__ Q,
                                                   const u16* __restrict__ Km,
                                                   const u16* __restrict__ Vt_g,
                                                   u16* __restrict__ O) {
  __shared__ u16 Klds[2][2][4096];  // [buf][half][64key x 64hd], XOR-swizzled 16B slots
  __shared__ u16 Vlds[2][2][4096];  // [buf][half][64hd x 64key'], key-permuted + swizzled
  const int tid = threadIdx.x;
  const int lane = tid & 63, w = tid >> 6;  // w = 0..7
  const int g = lane >> 4, r = lane & 15;
  const int orig = blockIdx.y * 8 + blockIdx.x;
  const int nid = (orig & 7) * 64 + (orig >> 3);  // each XCD: 8 contiguous bh groups
  const int qblk = nid & 7, bh = nid >> 3;
  const int b = bh >> 4, head = bh & 15;
  const size_t rowbase = (size_t)b * S_;
  const int colbase = head * 64;
  const int qw = qblk * 256 + w * 32;  // wave's 32 q rows

  bf16x8 qf0[2], qf1[2];
#pragma unroll
  for (int qh = 0; qh < 2; qh++) {
    const u16* qrow = Q + (rowbase + qw + qh * 16 + r) * D_ + colbase;
    qf0[qh] = __builtin_bit_cast(bf16x8, *(const us8*)(qrow + g * 8));
    qf1[qh] = __builtin_bit_cast(bf16x8, *(const us8*)(qrow + 32 + g * 8));
  }

  const int srow = tid >> 3;                       // 0..63 (512 threads)
  const int sslot = (tid & 7) ^ (srow & 7);        // pre-swizzled 16B slot
  const u16* Kg = Km + (rowbase + srow) * D_ + colbase + sslot * 8;
  const u16* Vg = Vt_g + ((size_t)bh * 64 + srow) * S_ + sslot * 8;

  const us8 onesw = {0x3F80, 0x3F80, 0x3F80, 0x3F80, 0x3F80, 0x3F80, 0x3F80, 0x3F80};
  const bf16x8 ones8 = __builtin_bit_cast(bf16x8, onesw);

  f32x4 lacc[2];
  f32x4 oacc[2][4];
#pragma unroll
  for (int qh = 0; qh < 2; qh++) {
    f32x4 z = {0.0f, 0.0f, 0.0f, 0.0f};
    lacc[qh] = z;
#pragma unroll
    for (int n = 0; n < 4; n++) oacc[qh][n] = z;
  }

  constexpr int NG = S_ / 128;  // 16

#define STAGE_GRP(t, bq_)                                                            \
  {                                                                                  \
    const int _t = (t), _b = (bq_);                                                  \
    _Pragma("unroll") for (int h = 0; h < 2; h++) {                                  \
      gload16(Kg + (size_t)(_t * 128 + h * 64) * D_, (char*)&Klds[_b][h][0] + w * 1024); \
      gload16(Vg + _t * 128 + h * 64, (char*)&Vlds[_b][h][0] + w * 1024);            \
    }                                                                                \
  }

  STAGE_GRP(0, 0);  // prologue

  for (int t = 0; t < NG; ++t) {
    const int buf = t & 1;
    if (t + 1 < NG) {
      STAGE_GRP(t + 1, buf ^ 1);
      asm volatile("s_waitcnt vmcnt(4)" ::: "memory");  // group t's own 4 loads retired
    } else {
      asm volatile("s_waitcnt vmcnt(0)" ::: "memory");
    }
    __builtin_amdgcn_s_barrier();
    asm volatile("" ::: "memory");

    // ---- QK half 0 ----
    f32x4 st0[4][2];
    __builtin_amdgcn_s_setprio(1);
#pragma unroll
    for (int f = 0; f < 4; f++) {
      const int row = f * 16 + r;
      const int sw7 = row & 7;
      const u16* Kc = &Klds[buf][0][0];
      const bf16x8 k0 = __builtin_bit_cast(bf16x8, *(const us8*)(Kc + row * 64 + (g ^ sw7) * 8));
      const bf16x8 k1 =
          __builtin_bit_cast(bf16x8, *(const us8*)(Kc + row * 64 + ((g + 4) ^ sw7) * 8));
#pragma unroll
      for (int qh = 0; qh < 2; qh++) {
        f32x4 z = {0.0f, 0.0f, 0.0f, 0.0f};
        st0[f][qh] = mfma16(k0, qf0[qh], z);
        st0[f][qh] = mfma16(k1, qf1[qh], st0[f][qh]);
      }
    }
    __builtin_amdgcn_s_setprio(0);
    // ---- exp2 half 0 ----
    bf16x8 paA0[2], paA1[2];
#pragma unroll
    for (int qh = 0; qh < 2; qh++) {
      u32 pw[8];
#pragma unroll
      for (int f = 0; f < 4; f++) {
        const float e0 = EXP2(st0[f][qh][0]);
        const float e1 = EXP2(st0[f][qh][1]);
        const float e2 = EXP2(st0[f][qh][2]);
        const float e3 = EXP2(st0[f][qh][3]);
        pw[f * 2] = cvtpk_bf16(e0, e1);
        pw[f * 2 + 1] = cvtpk_bf16(e2, e3);
      }
      const u32x4 a0w = {pw[0], pw[1], pw[2], pw[3]};
      const u32x4 a1w = {pw[4], pw[5], pw[6], pw[7]};
      paA0[qh] = __builtin_bit_cast(bf16x8, a0w);
      paA1[qh] = __builtin_bit_cast(bf16x8, a1w);
    }
    // ---- QK half 1 ----
    f32x4 st1[4][2];
    __builtin_amdgcn_s_setprio(1);
#pragma unroll
    for (int f = 0; f < 4; f++) {
      const int row = f * 16 + r;
      const int sw7 = row & 7;
      const u16* Kc = &Klds[buf][1][0];
      const bf16x8 k0 = __builtin_bit_cast(bf16x8, *(const us8*)(Kc + row * 64 + (g ^ sw7) * 8));
      const bf16x8 k1 =
          __builtin_bit_cast(bf16x8, *(const us8*)(Kc + row * 64 + ((g + 4) ^ sw7) * 8));
#pragma unroll
      for (int qh = 0; qh < 2; qh++) {
        f32x4 z = {0.0f, 0.0f, 0.0f, 0.0f};
        st1[f][qh] = mfma16(k0, qf0[qh], z);
        st1[f][qh] = mfma16(k1, qf1[qh], st1[f][qh]);
      }
    }
    // ---- PV half 0 + l half 0 ----
#pragma unroll
    for (int qh = 0; qh < 2; qh++) {
      lacc[qh] = mfma16(paA0[qh], ones8, lacc[qh]);
      lacc[qh] = mfma16(paA1[qh], ones8, lacc[qh]);
    }
#pragma unroll
    for (int n = 0; n < 4; n++) {
      const int row = n * 16 + r;
      const int sw7 = r & 7;
      const u16* Vc = &Vlds[buf][0][0];
      const bf16x8 vb0 = __builtin_bit_cast(bf16x8, *(const us8*)(Vc + row * 64 + (g ^ sw7) * 8));
      const bf16x8 vb1 =
          __builtin_bit_cast(bf16x8, *(const us8*)(Vc + row * 64 + ((4 + g) ^ sw7) * 8));
#pragma unroll
      for (int qh = 0; qh < 2; qh++) {
        oacc[qh][n] = mfma16(paA0[qh], vb0, oacc[qh][n]);
        oacc[qh][n] = mfma16(paA1[qh], vb1, oacc[qh][n]);
      }
    }
    __builtin_amdgcn_s_setprio(0);
    // ---- exp2 half 1 ----
    bf16x8 paB0[2], paB1[2];
#pragma unroll
    for (int qh = 0; qh < 2; qh++) {
      u32 pw[8];
#pragma unroll
      for (int f = 0; f < 4; f++) {
        const float e0 = EXP2(st1[f][qh][0]);
        const float e1 = EXP2(st1[f][qh][1]);
        const float e2 = EXP2(st1[f][qh][2]);
        const float e3 = EXP2(st1[f][qh][3]);
        pw[f * 2] = cvtpk_bf16(e0, e1);
        pw[f * 2 + 1] = cvtpk_bf16(e2, e3);
      }
      const u32x4 a0w = {pw[0], pw[1], pw[2], pw[3]};
      const u32x4 a1w = {pw[4], pw[5], pw[6], pw[7]};
      paB0[qh] = __builtin_bit_cast(bf16x8, a0w);
      paB1[qh] = __builtin_bit_cast(bf16x8, a1w);
    }
    // ---- PV half 1 + l half 1 ----
    __builtin_amdgcn_s_setprio(1);
#pragma unroll
    for (int qh = 0; qh < 2; qh++) {
      lacc[qh] = mfma16(paB0[qh], ones8, lacc[qh]);
      lacc[qh] = mfma16(paB1[qh], ones8, lacc[qh]);
    }
#pragma unroll
    for (int n = 0; n < 4; n++) {
      const int row = n * 16 + r;
      const int sw7 = r & 7;
      const u16* Vc = &Vlds[buf][1][0];
      const bf16x8 vb0 = __builtin_bit_cast(bf16x8, *(const us8*)(Vc + row * 64 + (g ^ sw7) * 8));
      const bf16x8 vb1 =
          __builtin_bit_cast(bf16x8, *(const us8*)(Vc + row * 64 + ((4 + g) ^ sw7) * 8));
#pragma unroll
      for (int qh = 0; qh < 2; qh++) {
        oacc[qh][n] = mfma16(paB0[qh], vb0, oacc[qh][n]);
        oacc[qh][n] = mfma16(paB1[qh], vb1, oacc[qh][n]);
      }
    }
    __builtin_amdgcn_s_setprio(0);

    asm volatile("" ::: "memory");
    __builtin_amdgcn_s_barrier();  // end of group: all waves past reads of this buffer
    asm volatile("" ::: "memory");
  }
#undef STAGE_GRP

  // lacc[qh][i] = l for q-row qw + qh*16 + 4g + i -> no shuffles
#pragma unroll
  for (int qh = 0; qh < 2; qh++) {
    float ld[4];
#pragma unroll
    for (int i = 0; i < 4; i++) ld[i] = 1.0f / lacc[qh][i];
#pragma unroll
    for (int n = 0; n < 4; n++)
#pragma unroll
      for (int i = 0; i < 4; i++)
        O[(rowbase + qw + qh * 16 + 4 * g + i) * D_ + colbase + n * 16 + r] =
            f2bf(oacc[qh][n][i] * ld[i]);
  }
}

// ---------------- launch ----------------
extern "C" void kernel_launch(void* const* d_in, const int* in_sizes, int n_in, void* d_out,
                              int out_size, void* d_ws, size_t ws_size, hipStream_t stream) {
  (void)in_sizes; (void)n_in; (void)out_size; (void)ws_size;
  const float* x = (const float*)d_in[0];
  const float* wq = (const float*)d_in[1];
  const float* bq = (const float*)d_in[2];
  const float* wk = (const float*)d_in[3];
  const float* bk = (const float*)d_in[4];
  const float* wv = (const float*)d_in[5];
  const float* bv = (const float*)d_in[6];
  const float* wo = (const float*)d_in[7];
  const float* bo = (const float*)d_in[8];
  const float* w1 = (const float*)d_in[9];
  const float* b1 = (const float*)d_in[10];
  const float* w2 = (const float*)d_in[11];
  const float* b2 = (const float*)d_in[12];
  const float* ln1a = (const float*)d_in[13];
  const float* ln1b = (const float*)d_in[14];
  const float* ln2a = (const float*)d_in[15];
  const float* ln2b = (const float*)d_in[16];

  char* ws = (char*)d_ws;
  const size_t MB = 1ull << 20;
  u16* wqkv = (u16*)(ws + 0 * MB);  // contiguous [3072][1024]: wq^T | wk^T | wv^T
  u16* wot = (u16*)(ws + 6 * MB);
  u16* w1t = (u16*)(ws + 8 * MB);
  u16* w2t = (u16*)(ws + 16 * MB);
  u16* xA = (u16*)(ws + 24 * MB);   // ln1 out -> attn out -> ln2 out (16MB)
  u16* qb = (u16*)(ws + 40 * MB);
  u16* kb = (u16*)(ws + 56 * MB);
  u16* vt = (u16*)(ws + 72 * MB);   // V^T [b,head,hd,s'] key-permuted (16MB)
  float* bcat = (float*)(ws + 88 * MB);  // [3072] f32; dead once QKV GEMM ran
  u16* ff1 = (u16*)(ws + 40 * MB);  // reuses q/k/bcat region after attention (64MB)
  u16* x1b = (u16*)(ws + 104 * MB); // bf16 residual stream x1 (16MB)

  const float QSCALE = 0.125f * 1.4426950408889634f;  // 1/sqrt(64) * log2(e)

  prep_kernel<<<14348, dim3(32, 8), 0, stream>>>(x, xA, ln1a, ln1b, wq, wk, wv, wo, w1, w2, bq,
                                                 bk, bv, wqkv, wot, w1t, w2t, bcat, QSCALE);
  gemm_bt256<2, false><<<dim3(12, 32), 512, 0, stream>>>(xA, wqkv, bcat, qb, kb, vt, 3072, 1024);
  attn_kernel<<<dim3(8, 64), 512, 0, stream>>>(qb, kb, vt, xA);
  gemm_bt128<0, 1><<<dim3(8, 64), 256, 0, stream>>>(xA, wot, bo, x, x1b, 1024, 1024);
  ln_bf16_kernel<<<8192, 256, 0, stream>>>(x1b, xA, ln2a, ln2b);
  gemm_bt256<0, true><<<dim3(16, 32), 512, 0, stream>>>(xA, w1t, b1, ff1, nullptr, nullptr, 4096,
                                                        1024);
  gemm_bt128<1, 2><<<dim3(8, 64), 256, 0, stream>>>(ff1, w2t, b2, x1b, (float*)d_out, 1024, 4096);
}

// Round 16
// 330.528 us; speedup vs baseline: 1.0439x; 1.0439x over previous
//
#include <hip/hip_runtime.h>

#define S_ 2048
#define D_ 1024

typedef unsigned short u16;
typedef unsigned int u32;
typedef __bf16 bf16x8 __attribute__((ext_vector_type(8)));
typedef unsigned short us8 __attribute__((ext_vector_type(8)));
typedef unsigned short us4 __attribute__((ext_vector_type(4)));
typedef unsigned int u32x4 __attribute__((ext_vector_type(4)));
typedef float f32x4 __attribute__((ext_vector_type(4)));

#if __has_builtin(__builtin_amdgcn_exp2f)
#define EXP2(x) __builtin_amdgcn_exp2f(x)
#else
#define EXP2(x) exp2f(x)
#endif

static __device__ __forceinline__ u16 f2bf(float f) {
  unsigned u = __builtin_bit_cast(unsigned, f);
  u += 0x7fffu + ((u >> 16) & 1u);   // RNE; inputs are finite
  return (u16)(u >> 16);
}

static __device__ __forceinline__ float bf2f(u16 h) {
  return __builtin_bit_cast(float, (u32)h << 16);
}

static __device__ __forceinline__ unsigned cvtpk_bf16(float lo, float hi) {
  unsigned r;
  asm("v_cvt_pk_bf16_f32 %0, %1, %2" : "=v"(r) : "v"(lo), "v"(hi));
  return r;
}

static __device__ __forceinline__ f32x4 mfma16(bf16x8 a, bf16x8 b, f32x4 c) {
  return __builtin_amdgcn_mfma_f32_16x16x32_bf16(a, b, c, 0, 0, 0);
}

static __device__ __forceinline__ void gload16(const void* g, void* lds) {
  // async global->LDS, 16B/lane; LDS dest = wave-uniform base + lane*16
  __builtin_amdgcn_global_load_lds((const __attribute__((address_space(1))) void*)g,
                                   (__attribute__((address_space(3))) void*)lds, 16, 0, 0);
}

// -------- fused prep: ln1 (8192 rows) + 6 weight transposes (64k x 32n tiles, us8 writes)
// -------- + bias concat, ONE launch --------
__global__ __launch_bounds__(256) void prep_kernel(
    const float* __restrict__ x, u16* __restrict__ xA, const float* __restrict__ ln1a,
    const float* __restrict__ ln1b, const float* __restrict__ wq, const float* __restrict__ wk,
    const float* __restrict__ wv, const float* __restrict__ wo, const float* __restrict__ w1,
    const float* __restrict__ w2, const float* __restrict__ bq, const float* __restrict__ bk,
    const float* __restrict__ bv, u16* __restrict__ wqkv, u16* __restrict__ wot,
    u16* __restrict__ w1t, u16* __restrict__ w2t, float* __restrict__ bcat, float qs) {
  const int bid = blockIdx.x;
  const int tid = threadIdx.y * 32 + threadIdx.x;
  if (bid < 8192) {  // ---- ln1 row ----
    const int row = bid;
    const float4 v = *(const float4*)(x + (size_t)row * D_ + tid * 4);
    float s = v.x + v.y + v.z + v.w;
    float ss = v.x * v.x + v.y * v.y + v.z * v.z + v.w * v.w;
#pragma unroll
    for (int off = 32; off >= 1; off >>= 1) {
      s += __shfl_xor(s, off);
      ss += __shfl_xor(ss, off);
    }
    __shared__ float red[8];
    const int w = tid >> 6, lane = tid & 63;
    if (lane == 0) { red[w] = s; red[4 + w] = ss; }
    __syncthreads();
    s = red[0] + red[1] + red[2] + red[3];
    ss = red[4] + red[5] + red[6] + red[7];
    const float mean = s * (1.0f / D_);
    const float var = (ss - s * mean) * (1.0f / (D_ - 1));
    const float inv = 1.0f / (sqrtf(var) + 1e-6f);
    const int j = tid * 4;
    const float4 av = *(const float4*)(ln1a + j);
    const float4 bv = *(const float4*)(ln1b + j);
    us4 o;
    o[0] = f2bf((v.x - mean) * inv * av.x + bv.x);
    o[1] = f2bf((v.y - mean) * inv * av.y + bv.y);
    o[2] = f2bf((v.z - mean) * inv * av.z + bv.z);
    o[3] = f2bf((v.w - mean) * inv * av.w + bv.w);
    *(us4*)(xA + (size_t)row * D_ + j) = o;
    return;
  }
  if (bid >= 14336) {  // ---- bias concat: 12 blocks x 256 ----
    const int i = (bid - 14336) * 256 + tid;
    bcat[i] = (i < 1024) ? bq[i] * qs : ((i < 2048) ? bk[i - 1024] : bv[i - 2048]);
    return;
  }
  // ---- weight transpose: tile = 64 k x 32 n ----
  const int tb = bid - 8192;
  const float* in;
  u16* out;
  int K, N, idx;
  float sc = 1.0f;
  if (tb < 2048) {
    K = 1024; N = 1024; idx = tb & 511;
    if (tb < 512)        { in = wq; out = wqkv;             sc = qs; }
    else if (tb < 1024)  { in = wk; out = wqkv + (1 << 20); }
    else if (tb < 1536)  { in = wv; out = wqkv + (2 << 20); }
    else                 { in = wo; out = wot; }
  } else if (tb < 4096) {
    in = w1; out = w1t; K = 1024; N = 4096; idx = tb - 2048;
  } else {
    in = w2; out = w2t; K = 4096; N = 1024; idx = tb - 4096;
  }
  const int nk = K >> 6;
  const int k0 = (idx % nk) * 64, n0 = (idx / nk) * 32;
  __shared__ float t[32][65];
  const int kk = tid >> 2, nj = (tid & 3) * 8;
  const float* src = in + (size_t)(k0 + kk) * N + n0 + nj;
  const float4 v0 = *(const float4*)(src);
  const float4 v1 = *(const float4*)(src + 4);
  t[nj + 0][kk] = v0.x; t[nj + 1][kk] = v0.y; t[nj + 2][kk] = v0.z; t[nj + 3][kk] = v0.w;
  t[nj + 4][kk] = v1.x; t[nj + 5][kk] = v1.y; t[nj + 6][kk] = v1.z; t[nj + 7][kk] = v1.w;
  __syncthreads();
  const int row = tid >> 3, kb = (tid & 7) * 8;
  us8 o;
#pragma unroll
  for (int j = 0; j < 8; j++) o[j] = f2bf(t[row][kb + j] * sc);
  *(us8*)(out + (size_t)(n0 + row) * K + k0 + kb) = o;
}

// ---------------- LayerNorm (bf16 input variant for ln2) ----------------
__global__ __launch_bounds__(256) void ln_bf16_kernel(const u16* __restrict__ in,
                                                      u16* __restrict__ out,
                                                      const float* __restrict__ alpha,
                                                      const float* __restrict__ beta) {
  const int row = blockIdx.x;
  const int tid = threadIdx.x;
  const us4 h = *(const us4*)(in + (size_t)row * D_ + tid * 4);
  float v0 = bf2f(h[0]), v1 = bf2f(h[1]), v2 = bf2f(h[2]), v3 = bf2f(h[3]);
  float s = v0 + v1 + v2 + v3;
  float ss = v0 * v0 + v1 * v1 + v2 * v2 + v3 * v3;
#pragma unroll
  for (int off = 32; off >= 1; off >>= 1) {
    s += __shfl_xor(s, off);
    ss += __shfl_xor(ss, off);
  }
  __shared__ float red[8];
  const int w = tid >> 6, lane = tid & 63;
  if (lane == 0) { red[w] = s; red[4 + w] = ss; }
  __syncthreads();
  s = red[0] + red[1] + red[2] + red[3];
  ss = red[4] + red[5] + red[6] + red[7];
  const float mean = s * (1.0f / D_);
  const float var = (ss - s * mean) * (1.0f / (D_ - 1));
  const float inv = 1.0f / (sqrtf(var) + 1e-6f);
  const int j = tid * 4;
  const float4 av = *(const float4*)(alpha + j);
  const float4 bv = *(const float4*)(beta + j);
  us4 o;
  o[0] = f2bf((v0 - mean) * inv * av.x + bv.x);
  o[1] = f2bf((v1 - mean) * inv * av.y + bv.y);
  o[2] = f2bf((v2 - mean) * inv * av.z + bv.z);
  o[3] = f2bf((v3 - mean) * inv * av.w + bv.w);
  *(us4*)(out + (size_t)row * D_ + j) = o;
}

// ---------------- GEMM 128x128: 2-buffer, counted vmcnt(8), 64KB LDS -> 2 blocks/CU -------
// OM: 0 = bf16 out, 1 = f32 out. RESID: 0 none, 1 f32, 2 bf16.
template <int OM, int RESID>
__global__ __launch_bounds__(256, 2) void gemm_bt128(const u16* __restrict__ A,
                                                     const u16* __restrict__ Bt,
                                                     const float* __restrict__ bias,
                                                     const void* __restrict__ resid,
                                                     void* __restrict__ outp, int N, int K) {
  __shared__ u16 lds[2 * 16384];  // 2 x (A 128x64 + B 128x64) u16 = 64 KiB
  const int tid = threadIdx.x;
  const int lane = tid & 63, w = tid >> 6;
  const int g = lane >> 4, r = lane & 15;
  const int wr = w >> 1, wc = w & 1;  // 2M x 2N
  const int gx = gridDim.x;
  const int nwg = gx * gridDim.y;
  const int orig = blockIdx.y * gx + blockIdx.x;
  const int nid = (orig & 7) * (nwg >> 3) + (orig >> 3);  // nwg % 8 == 0
  const int bx = nid % gx, by = nid / gx;
  const size_t row0 = (size_t)by * 128;
  const int col0 = bx * 128;

  float bias4[4];
#pragma unroll
  for (int n = 0; n < 4; n++) bias4[n] = bias[col0 + wc * 64 + n * 16 + r];

  f32x4 acc[4][4];
#pragma unroll
  for (int m = 0; m < 4; m++)
#pragma unroll
    for (int n = 0; n < 4; n++) {
      f32x4 z = {bias4[n], bias4[n], bias4[n], bias4[n]};
      acc[m][n] = z;
    }

  const int lrow = tid >> 3;                       // 0..31 (row within 32-row chunk)
  const int scol = 8 * ((tid & 7) ^ (lrow & 7));   // pre-swizzled source col
  const u16* gA = A + (row0 + lrow) * (size_t)K + scol;
  const u16* gB = Bt + ((size_t)col0 + lrow) * (size_t)K + scol;
  const int nt = K >> 6;
  const int sw = (r & 7) << 3;

  {
    u16* d = lds + w * 512;
#pragma unroll
    for (int j = 0; j < 4; j++) gload16(gA + (size_t)(j * 32) * K, d + j * 2048);
#pragma unroll
    for (int j = 0; j < 4; j++) gload16(gB + (size_t)(j * 32) * K, d + 8192 + j * 2048);
  }

  for (int t = 0; t < nt; ++t) {
    const u16* As_ = lds + (t & 1) * 16384;
    const u16* Bs_ = As_ + 8192;
    if (t + 1 < nt) {
      u16* d = lds + ((t + 1) & 1) * 16384 + w * 512;
      const size_t ko = (size_t)(t + 1) * 64;
#pragma unroll
      for (int j = 0; j < 4; j++) gload16(gA + (size_t)(j * 32) * K + ko, d + j * 2048);
#pragma unroll
      for (int j = 0; j < 4; j++) gload16(gB + (size_t)(j * 32) * K + ko, d + 8192 + j * 2048);
      asm volatile("s_waitcnt vmcnt(8)" ::: "memory");
    } else {
      asm volatile("s_waitcnt vmcnt(0)" ::: "memory");
    }
    __builtin_amdgcn_s_barrier();
    asm volatile("" ::: "memory");

    bf16x8 bfr[2][4];
#pragma unroll
    for (int kk = 0; kk < 2; kk++)
#pragma unroll
      for (int n = 0; n < 4; n++)
        bfr[kk][n] = __builtin_bit_cast(
            bf16x8, *(const us8*)(Bs_ + (wc * 64 + n * 16 + r) * 64 + ((kk * 32 + g * 8) ^ sw)));

#pragma unroll
    for (int p = 0; p < 4; ++p) {
      const int row = wr * 64 + p * 16 + r;
      bf16x8 a0 = __builtin_bit_cast(bf16x8, *(const us8*)(As_ + row * 64 + ((g * 8) ^ sw)));
      bf16x8 a1 = __builtin_bit_cast(bf16x8, *(const us8*)(As_ + row * 64 + ((32 + g * 8) ^ sw)));
      asm volatile("" ::: "memory");
      if (p > 0) __builtin_amdgcn_s_barrier();  // barrier-wait hides the ds_read latency
      asm volatile("s_waitcnt lgkmcnt(0)" ::: "memory");
      __builtin_amdgcn_sched_barrier(0);  // rule 18
      __builtin_amdgcn_s_setprio(1);
#pragma unroll
      for (int n = 0; n < 4; n++) {
        acc[p][n] = mfma16(a0, bfr[0][n], acc[p][n]);
        acc[p][n] = mfma16(a1, bfr[1][n], acc[p][n]);
      }
      __builtin_amdgcn_s_setprio(0);
    }
    asm volatile("" ::: "memory");
    __builtin_amdgcn_s_barrier();  // tile boundary
  }

#pragma unroll
  for (int m = 0; m < 4; m++)
#pragma unroll
    for (int n = 0; n < 4; n++)
#pragma unroll
      for (int i = 0; i < 4; i++) {
        const size_t rg = row0 + wr * 64 + m * 16 + 4 * g + i;
        const int cg = col0 + wc * 64 + n * 16 + r;
        float v = acc[m][n][i];
        if (RESID == 1) v += ((const float*)resid)[rg * N + cg];
        if (RESID == 2) v += bf2f(((const u16*)resid)[rg * N + cg]);
        if (OM == 1)
          ((float*)outp)[rg * N + cg] = v;
        else
          ((u16*)outp)[rg * N + cg] = f2bf(v);
      }
}

// ------------- GEMM 256x256: 2-buffer, 4-phase, vmcnt(8), barrier-hidden lgkm -------------
// OM: 0 = bf16 out (+RELU), 2 = fused QKV (seg0->q, seg1->k, seg2->V^T key-permuted)
template <int OM, bool RELU>
__global__ __launch_bounds__(512, 2) void gemm_bt256(const u16* __restrict__ A,
                                                     const u16* __restrict__ Bt,
                                                     const float* __restrict__ bias,
                                                     void* __restrict__ outp,
                                                     void* __restrict__ out1,
                                                     void* __restrict__ out2, int N, int K) {
  __shared__ u16 lds[2 * 32768];
  const int tid = threadIdx.x;
  const int lane = tid & 63, w = tid >> 6;
  const int g = lane >> 4, r = lane & 15;
  const int wr = w >> 2, wc = w & 3;  // 2M x 4N
  const int gx = gridDim.x;
  const int nwg = gx * gridDim.y;
  const int orig = blockIdx.y * gx + blockIdx.x;
  const int nid = (orig & 7) * (nwg >> 3) + (orig >> 3);
  const int bx = nid % gx, by = nid / gx;
  const size_t row0 = (size_t)by * 256;
  const int col0 = bx * 256;

  float bias4[4];
#pragma unroll
  for (int n = 0; n < 4; n++) bias4[n] = bias[col0 + wc * 64 + n * 16 + r];

  f32x4 acc[8][4];
#pragma unroll
  for (int m = 0; m < 8; m++)
#pragma unroll
    for (int n = 0; n < 4; n++) {
      f32x4 z = {bias4[n], bias4[n], bias4[n], bias4[n]};
      acc[m][n] = z;
    }

  const int lrow = tid >> 3;                       // 0..63
  const int scol = 8 * ((tid & 7) ^ (lrow & 7));   // pre-swizzled source col
  const u16* gA = A + (row0 + lrow) * (size_t)K + scol;
  const u16* gB = Bt + ((size_t)col0 + lrow) * (size_t)K + scol;
  const int nt = K >> 6;
  const int sw = (r & 7) << 3;

  {
    u16* d = lds + w * 512;
#pragma unroll
    for (int j = 0; j < 4; j++) gload16(gA + (size_t)(j * 64) * K, d + j * 4096);
#pragma unroll
    for (int j = 0; j < 4; j++) gload16(gB + (size_t)(j * 64) * K, d + 16384 + j * 4096);
  }

  for (int t = 0; t < nt; ++t) {
    const u16* As_ = lds + (t & 1) * 32768;
    const u16* Bs_ = As_ + 16384;
    if (t + 1 < nt) {
      u16* d = lds + ((t + 1) & 1) * 32768 + w * 512;
      const size_t ko = (size_t)(t + 1) * 64;
#pragma unroll
      for (int j = 0; j < 4; j++) gload16(gA + (size_t)(j * 64) * K + ko, d + j * 4096);
#pragma unroll
      for (int j = 0; j < 4; j++) gload16(gB + (size_t)(j * 64) * K + ko, d + 16384 + j * 4096);
      asm volatile("s_waitcnt vmcnt(8)" ::: "memory");
    } else {
      asm volatile("s_waitcnt vmcnt(0)" ::: "memory");
    }
    __builtin_amdgcn_s_barrier();
    asm volatile("" ::: "memory");

    bf16x8 bfr[2][4];
#pragma unroll
    for (int kk = 0; kk < 2; kk++)
#pragma unroll
      for (int n = 0; n < 4; n++)
        bfr[kk][n] = __builtin_bit_cast(
            bf16x8, *(const us8*)(Bs_ + (wc * 64 + n * 16 + r) * 64 + ((kk * 32 + g * 8) ^ sw)));

#pragma unroll
    for (int p = 0; p < 4; ++p) {
      bf16x8 af[2][2];
#pragma unroll
      for (int mm = 0; mm < 2; mm++) {
        const int row = wr * 128 + (p * 2 + mm) * 16 + r;
        af[0][mm] = __builtin_bit_cast(bf16x8, *(const us8*)(As_ + row * 64 + ((g * 8) ^ sw)));
        af[1][mm] =
            __builtin_bit_cast(bf16x8, *(const us8*)(As_ + row * 64 + ((32 + g * 8) ^ sw)));
      }
      asm volatile("" ::: "memory");
      if (p > 0) __builtin_amdgcn_s_barrier();
      asm volatile("s_waitcnt lgkmcnt(0)" ::: "memory");
      __builtin_amdgcn_sched_barrier(0);
      __builtin_amdgcn_s_setprio(1);
#pragma unroll
      for (int mm = 0; mm < 2; mm++)
#pragma unroll
        for (int n = 0; n < 4; n++) {
          acc[p * 2 + mm][n] = mfma16(af[0][mm], bfr[0][n], acc[p * 2 + mm][n]);
          acc[p * 2 + mm][n] = mfma16(af[1][mm], bfr[1][n], acc[p * 2 + mm][n]);
        }
      __builtin_amdgcn_s_setprio(0);
    }
    asm volatile("" ::: "memory");
    __builtin_amdgcn_s_barrier();
  }

#pragma unroll
  for (int m = 0; m < 8; m++)
#pragma unroll
    for (int n = 0; n < 4; n++) {
      if (OM == 2) {
        const int seg = col0 >> 10;
        const int cl = (col0 & 1023) + wc * 64 + n * 16 + r;
        if (seg == 2) {
          // V^T [b,head,hd,s'] with key-permuted s within each 64-tile
          const int head = cl >> 6, hd = cl & 63;
          const size_t rg0 = row0 + wr * 128 + m * 16 + 4 * g;
          const int b = (int)(rg0 >> 11), s0 = (int)(rg0 & 2047);
          const int s0p = (s0 & ~63) | (s0 & 32) | ((s0 << 1) & 24) | ((s0 >> 2) & 4);
          us4 o;
#pragma unroll
          for (int i = 0; i < 4; i++) o[i] = f2bf(acc[m][n][i]);
          *(us4*)((u16*)out2 + (((size_t)(b * 16 + head) * 64 + hd) * S_ + s0p)) = o;
        } else {
          u16* dst = (u16*)(seg == 0 ? outp : out1);
#pragma unroll
          for (int i = 0; i < 4; i++) {
            const size_t rg = row0 + wr * 128 + m * 16 + 4 * g + i;
            dst[rg * D_ + cl] = f2bf(acc[m][n][i]);
          }
        }
      } else {
#pragma unroll
        for (int i = 0; i < 4; i++) {
          const size_t rg = row0 + wr * 128 + m * 16 + 4 * g + i;
          const int cg = col0 + wc * 64 + n * 16 + r;
          float v = acc[m][n][i];
          if (RELU) v = fmaxf(v, 0.0f);
          ((u16*)outp)[rg * N + cg] = f2bf(v);
        }
      }
    }
}

// ------------- Flash attention: KVBLK=128, 8 waves/block (4 waves/SIMD occupancy) ---------
// Block = 512 thr = 8 waves x 32 q rows = 256 q rows; grid (8,64) = 512 blocks = 2/CU.
// Per 128-key group: ONE stage (4 gloads/wave), counted vmcnt(4)+barrier, compute
// QK(h0)->exp2(h0)->QK(h1)||PV(h0)->exp2(h1)->PV(h1), ONE end barrier.
// XCD bh-affinity swizzle; no-max softmax; l on the MFMA pipe via B=ones.
__global__ __launch_bounds__(512) void attn_kernel(const u16* __restrict__ Q,
                                                   const u16* __restrict__ Km,
                                                   const u16* __restrict__ Vt_g,
                                                   u16* __restrict__ O) {
  __shared__ u16 Klds[2][2][4096];  // [buf][half][64key x 64hd], XOR-swizzled 16B slots
  __shared__ u16 Vlds[2][2][4096];  // [buf][half][64hd x 64key'], key-permuted + swizzled
  const int tid = threadIdx.x;
  const int lane = tid & 63, w = tid >> 6;  // w = 0..7
  const int g = lane >> 4, r = lane & 15;
  const int orig = blockIdx.y * 8 + blockIdx.x;
  const int nid = (orig & 7) * 64 + (orig >> 3);  // each XCD: 8 contiguous bh groups
  const int qblk = nid & 7, bh = nid >> 3;
  const int b = bh >> 4, head = bh & 15;
  const size_t rowbase = (size_t)b * S_;
  const int colbase = head * 64;
  const int qw = qblk * 256 + w * 32;  // wave's 32 q rows

  bf16x8 qf0[2], qf1[2];
#pragma unroll
  for (int qh = 0; qh < 2; qh++) {
    const u16* qrow = Q + (rowbase + qw + qh * 16 + r) * D_ + colbase;
    qf0[qh] = __builtin_bit_cast(bf16x8, *(const us8*)(qrow + g * 8));
    qf1[qh] = __builtin_bit_cast(bf16x8, *(const us8*)(qrow + 32 + g * 8));
  }

  const int srow = tid >> 3;                       // 0..63 (512 threads)
  const int sslot = (tid & 7) ^ (srow & 7);        // pre-swizzled 16B slot
  const u16* Kg = Km + (rowbase + srow) * D_ + colbase + sslot * 8;
  const u16* Vg = Vt_g + ((size_t)bh * 64 + srow) * S_ + sslot * 8;

  const us8 onesw = {0x3F80, 0x3F80, 0x3F80, 0x3F80, 0x3F80, 0x3F80, 0x3F80, 0x3F80};
  const bf16x8 ones8 = __builtin_bit_cast(bf16x8, onesw);

  f32x4 lacc[2];
  f32x4 oacc[2][4];
#pragma unroll
  for (int qh = 0; qh < 2; qh++) {
    f32x4 z = {0.0f, 0.0f, 0.0f, 0.0f};
    lacc[qh] = z;
#pragma unroll
    for (int n = 0; n < 4; n++) oacc[qh][n] = z;
  }

  constexpr int NG = S_ / 128;  // 16

#define STAGE_GRP(t, bq_)                                                            \
  {                                                                                  \
    const int _t = (t), _b = (bq_);                                                  \
    _Pragma("unroll") for (int h = 0; h < 2; h++) {                                  \
      gload16(Kg + (size_t)(_t * 128 + h * 64) * D_, (char*)&Klds[_b][h][0] + w * 1024); \
      gload16(Vg + _t * 128 + h * 64, (char*)&Vlds[_b][h][0] + w * 1024);            \
    }                                                                                \
  }

  STAGE_GRP(0, 0);  // prologue

  for (int t = 0; t < NG; ++t) {
    const int buf = t & 1;
    if (t + 1 < NG) {
      STAGE_GRP(t + 1, buf ^ 1);
      asm volatile("s_waitcnt vmcnt(4)" ::: "memory");  // group t's own 4 loads retired
    } else {
      asm volatile("s_waitcnt vmcnt(0)" ::: "memory");
    }
    __builtin_amdgcn_s_barrier();
    asm volatile("" ::: "memory");

    // ---- QK half 0 ----
    f32x4 st0[4][2];
    __builtin_amdgcn_s_setprio(1);
#pragma unroll
    for (int f = 0; f < 4; f++) {
      const int row = f * 16 + r;
      const int sw7 = row & 7;
      const u16* Kc = &Klds[buf][0][0];
      const bf16x8 k0 = __builtin_bit_cast(bf16x8, *(const us8*)(Kc + row * 64 + (g ^ sw7) * 8));
      const bf16x8 k1 =
          __builtin_bit_cast(bf16x8, *(const us8*)(Kc + row * 64 + ((g + 4) ^ sw7) * 8));
#pragma unroll
      for (int qh = 0; qh < 2; qh++) {
        f32x4 z = {0.0f, 0.0f, 0.0f, 0.0f};
        st0[f][qh] = mfma16(k0, qf0[qh], z);
        st0[f][qh] = mfma16(k1, qf1[qh], st0[f][qh]);
      }
    }
    __builtin_amdgcn_s_setprio(0);
    // ---- exp2 half 0 ----
    bf16x8 paA0[2], paA1[2];
#pragma unroll
    for (int qh = 0; qh < 2; qh++) {
      u32 pw[8];
#pragma unroll
      for (int f = 0; f < 4; f++) {
        const float e0 = EXP2(st0[f][qh][0]);
        const float e1 = EXP2(st0[f][qh][1]);
        const float e2 = EXP2(st0[f][qh][2]);
        const float e3 = EXP2(st0[f][qh][3]);
        pw[f * 2] = cvtpk_bf16(e0, e1);
        pw[f * 2 + 1] = cvtpk_bf16(e2, e3);
      }
      const u32x4 a0w = {pw[0], pw[1], pw[2], pw[3]};
      const u32x4 a1w = {pw[4], pw[5], pw[6], pw[7]};
      paA0[qh] = __builtin_bit_cast(bf16x8, a0w);
      paA1[qh] = __builtin_bit_cast(bf16x8, a1w);
    }
    // ---- QK half 1 ----
    f32x4 st1[4][2];
    __builtin_amdgcn_s_setprio(1);
#pragma unroll
    for (int f = 0; f < 4; f++) {
      const int row = f * 16 + r;
      const int sw7 = row & 7;
      const u16* Kc = &Klds[buf][1][0];
      const bf16x8 k0 = __builtin_bit_cast(bf16x8, *(const us8*)(Kc + row * 64 + (g ^ sw7) * 8));
      const bf16x8 k1 =
          __builtin_bit_cast(bf16x8, *(const us8*)(Kc + row * 64 + ((g + 4) ^ sw7) * 8));
#pragma unroll
      for (int qh = 0; qh < 2; qh++) {
        f32x4 z = {0.0f, 0.0f, 0.0f, 0.0f};
        st1[f][qh] = mfma16(k0, qf0[qh], z);
        st1[f][qh] = mfma16(k1, qf1[qh], st1[f][qh]);
      }
    }
    // ---- PV half 0 + l half 0 ----
#pragma unroll
    for (int qh = 0; qh < 2; qh++) {
      lacc[qh] = mfma16(paA0[qh], ones8, lacc[qh]);
      lacc[qh] = mfma16(paA1[qh], ones8, lacc[qh]);
    }
#pragma unroll
    for (int n = 0; n < 4; n++) {
      const int row = n * 16 + r;
      const int sw7 = r & 7;
      const u16* Vc = &Vlds[buf][0][0];
      const bf16x8 vb0 = __builtin_bit_cast(bf16x8, *(const us8*)(Vc + row * 64 + (g ^ sw7) * 8));
      const bf16x8 vb1 =
          __builtin_bit_cast(bf16x8, *(const us8*)(Vc + row * 64 + ((4 + g) ^ sw7) * 8));
#pragma unroll
      for (int qh = 0; qh < 2; qh++) {
        oacc[qh][n] = mfma16(paA0[qh], vb0, oacc[qh][n]);
        oacc[qh][n] = mfma16(paA1[qh], vb1, oacc[qh][n]);
      }
    }
    __builtin_amdgcn_s_setprio(0);
    // ---- exp2 half 1 ----
    bf16x8 paB0[2], paB1[2];
#pragma unroll
    for (int qh = 0; qh < 2; qh++) {
      u32 pw[8];
#pragma unroll
      for (int f = 0; f < 4; f++) {
        const float e0 = EXP2(st1[f][qh][0]);
        const float e1 = EXP2(st1[f][qh][1]);
        const float e2 = EXP2(st1[f][qh][2]);
        const float e3 = EXP2(st1[f][qh][3]);
        pw[f * 2] = cvtpk_bf16(e0, e1);
        pw[f * 2 + 1] = cvtpk_bf16(e2, e3);
      }
      const u32x4 a0w = {pw[0], pw[1], pw[2], pw[3]};
      const u32x4 a1w = {pw[4], pw[5], pw[6], pw[7]};
      paB0[qh] = __builtin_bit_cast(bf16x8, a0w);
      paB1[qh] = __builtin_bit_cast(bf16x8, a1w);
    }
    // ---- PV half 1 + l half 1 ----
    __builtin_amdgcn_s_setprio(1);
#pragma unroll
    for (int qh = 0; qh < 2; qh++) {
      lacc[qh] = mfma16(paB0[qh], ones8, lacc[qh]);
      lacc[qh] = mfma16(paB1[qh], ones8, lacc[qh]);
    }
#pragma unroll
    for (int n = 0; n < 4; n++) {
      const int row = n * 16 + r;
      const int sw7 = r & 7;
      const u16* Vc = &Vlds[buf][1][0];
      const bf16x8 vb0 = __builtin_bit_cast(bf16x8, *(const us8*)(Vc + row * 64 + (g ^ sw7) * 8));
      const bf16x8 vb1 =
          __builtin_bit_cast(bf16x8, *(const us8*)(Vc + row * 64 + ((4 + g) ^ sw7) * 8));
#pragma unroll
      for (int qh = 0; qh < 2; qh++) {
        oacc[qh][n] = mfma16(paB0[qh], vb0, oacc[qh][n]);
        oacc[qh][n] = mfma16(paB1[qh], vb1, oacc[qh][n]);
      }
    }
    __builtin_amdgcn_s_setprio(0);

    asm volatile("" ::: "memory");
    __builtin_amdgcn_s_barrier();  // end of group: all waves past reads of this buffer
    asm volatile("" ::: "memory");
  }
#undef STAGE_GRP

  // lacc[qh][i] = l for q-row qw + qh*16 + 4g + i -> no shuffles
#pragma unroll
  for (int qh = 0; qh < 2; qh++) {
    float ld[4];
#pragma unroll
    for (int i = 0; i < 4; i++) ld[i] = 1.0f / lacc[qh][i];
#pragma unroll
    for (int n = 0; n < 4; n++)
#pragma unroll
      for (int i = 0; i < 4; i++)
        O[(rowbase + qw + qh * 16 + 4 * g + i) * D_ + colbase + n * 16 + r] =
            f2bf(oacc[qh][n][i] * ld[i]);
  }
}

// ---------------- launch ----------------
extern "C" void kernel_launch(void* const* d_in, const int* in_sizes, int n_in, void* d_out,
                              int out_size, void* d_ws, size_t ws_size, hipStream_t stream) {
  (void)in_sizes; (void)n_in; (void)out_size; (void)ws_size;
  const float* x = (const float*)d_in[0];
  const float* wq = (const float*)d_in[1];
  const float* bq = (const float*)d_in[2];
  const float* wk = (const float*)d_in[3];
  const float* bk = (const float*)d_in[4];
  const float* wv = (const float*)d_in[5];
  const float* bv = (const float*)d_in[6];
  const float* wo = (const float*)d_in[7];
  const float* bo = (const float*)d_in[8];
  const float* w1 = (const float*)d_in[9];
  const float* b1 = (const float*)d_in[10];
  const float* w2 = (const float*)d_in[11];
  const float* b2 = (const float*)d_in[12];
  const float* ln1a = (const float*)d_in[13];
  const float* ln1b = (const float*)d_in[14];
  const float* ln2a = (const float*)d_in[15];
  const float* ln2b = (const float*)d_in[16];

  char* ws = (char*)d_ws;
  const size_t MB = 1ull << 20;
  u16* wqkv = (u16*)(ws + 0 * MB);  // contiguous [3072][1024]: wq^T | wk^T | wv^T
  u16* wot = (u16*)(ws + 6 * MB);
  u16* w1t = (u16*)(ws + 8 * MB);
  u16* w2t = (u16*)(ws + 16 * MB);
  u16* xA = (u16*)(ws + 24 * MB);   // ln1 out -> attn out -> ln2 out (16MB)
  u16* qb = (u16*)(ws + 40 * MB);
  u16* kb = (u16*)(ws + 56 * MB);
  u16* vt = (u16*)(ws + 72 * MB);   // V^T [b,head,hd,s'] key-permuted (16MB)
  float* bcat = (float*)(ws + 88 * MB);  // [3072] f32; dead once QKV GEMM ran
  u16* ff1 = (u16*)(ws + 40 * MB);  // reuses q/k/bcat region after attention (64MB)
  u16* x1b = (u16*)(ws + 104 * MB); // bf16 residual stream x1 (16MB)

  const float QSCALE = 0.125f * 1.4426950408889634f;  // 1/sqrt(64) * log2(e)

  prep_kernel<<<14348, dim3(32, 8), 0, stream>>>(x, xA, ln1a, ln1b, wq, wk, wv, wo, w1, w2, bq,
                                                 bk, bv, wqkv, wot, w1t, w2t, bcat, QSCALE);
  gemm_bt256<2, false><<<dim3(12, 32), 512, 0, stream>>>(xA, wqkv, bcat, qb, kb, vt, 3072, 1024);
  attn_kernel<<<dim3(8, 64), 512, 0, stream>>>(qb, kb, vt, xA);
  gemm_bt128<0, 1><<<dim3(8, 64), 256, 0, stream>>>(xA, wot, bo, x, x1b, 1024, 1024);
  ln_bf16_kernel<<<8192, 256, 0, stream>>>(x1b, xA, ln2a, ln2b);
  gemm_bt256<0, true><<<dim3(16, 32), 512, 0, stream>>>(xA, w1t, b1, ff1, nullptr, nullptr, 4096,
                                                        1024);
  gemm_bt128<1, 2><<<dim3(8, 64), 256, 0, stream>>>(ff1, w2t, b2, x1b, (float*)d_out, 1024, 4096);
}